// Round 4
// baseline (38.180 us; speedup 1.0000x reference)
//
#include <hip/hip_runtime.h>

// x,y float32 (B=2, C=1, D=32, H=128, W=128).
// out = mean over [B,C,D,3,H,3,W,3] of |d_c - d_n|, d = x - y, zero-padded
// neighbors. Computed EXACTLY as the reference: per voxel, sum |c - n| over
// all 27 zero-padded neighbors (center contributes 0).
constexpr int Dd = 32, Hh = 128, Ww = 128, Bv = 2;
constexpr int NVOX = Bv * Dd * Hh * Ww;     // 1,048,576
constexpr int BLK  = 256;

constexpr int TD = 2, TH = 4;               // tile 2 x 4 x 128 (full W rows)
constexpr int ZT = Dd / TD;                 // 16
constexpr int YT = Hh / TH;                 // 32
constexpr int NBLK = Bv * ZT * YT;          // 1024 blocks = 4/CU
constexpr int LSTR = 136;                   // floats/LDS row; k = w + 4 -> 16B-aligned f4
constexpr int RZ = TD + 2, RY = TH + 2;     // halo rows: z in [z0-1,z0+2], y in [y0-1,y0+4]
constexpr int NROWS = RZ * RY;              // 24
constexpr int NSLOT = LSTR / 4;             // 34 float4 slots per row
constexpr int NITEM = NROWS * NSLOT;        // 816

__global__ void __launch_bounds__(BLK)
cdl_kernel(const float* __restrict__ xg, const float* __restrict__ yg,
           float* __restrict__ partials, unsigned int* __restrict__ counter,
           float* __restrict__ out)
{
    __shared__ float lds[NROWS * LSTR];     // 13,056 B
    __shared__ float smem[BLK / 64];
    __shared__ int   lastFlag;

    const int tid = threadIdx.x;
    // XCD-aware bijective swizzle (NBLK % 8 == 0)
    const int bid = (blockIdx.x & 7) * (NBLK / 8) + (blockIdx.x >> 3);

    int t = bid;
    const int yt  = t & (YT - 1); t >>= 5;
    const int zt  = t & (ZT - 1); t >>= 4;
    const int vol = t;
    const int z0 = zt * TD, y0 = yt * TH;
    const size_t vbase = (size_t)vol * Dd * Hh * Ww;

    // ---- stage d = x - y halo tile into LDS (zero outside volume / w-pad) ----
#pragma unroll
    for (int p = 0; p < 4; ++p) {
        const int idx = p * BLK + tid;
        if (idx < NITEM) {
            const int row  = idx / NSLOT;
            const int slot = idx - row * NSLOT;
            const int lzr  = row / RY;
            const int lyr  = row - lzr * RY;
            const int gz = z0 + lzr - 1;        // [z0-1, z0+2]
            const int gy = y0 + lyr - 1;        // [y0-1, y0+4]
            const int w  = 4 * slot - 4;        // float4 covers w..w+3
            float4 v = make_float4(0.f, 0.f, 0.f, 0.f);
            if ((unsigned)gz < (unsigned)Dd && (unsigned)gy < (unsigned)Hh &&
                (unsigned)w < (unsigned)Ww) {   // w%4==0 -> w<=124 when true
                const size_t g = vbase + ((size_t)gz * Hh + gy) * Ww + w;
                const float4 a = *(const float4*)(xg + g);
                const float4 b = *(const float4*)(yg + g);
                v = make_float4(a.x - b.x, a.y - b.y, a.z - b.z, a.w - b.w);
            }
            *(float4*)&lds[row * LSTR + 4 * slot] = v;
        }
    }
    __syncthreads();

    // ---- compute: thread -> one (z,y) row, 4 voxels (w = 4j..4j+3) ----
    const int j  = tid & 31;                    // w-segment
    const int rr = tid >> 5;                    // 0..7
    const int lz = rr >> 2;                     // 0..1
    const int ly = rr & 3;                      // 0..3
    const int k0 = 4 * j + 4;

    const float* crow = &lds[((lz + 1) * RY + (ly + 1)) * LSTR + k0];
    const float4 c = *(const float4*)crow;

    float s = 0.f;
#pragma unroll
    for (int dz = 0; dz < 3; ++dz) {
#pragma unroll
        for (int dy = 0; dy < 3; ++dy) {
            const float* rp = &lds[((lz + dz) * RY + (ly + dy)) * LSTR + k0];
            const float4 A = *(const float4*)rp;
            const float  m = rp[-1];            // w-1 edge
            const float  q = rp[4];             // w+4 edge
            s += fabsf(c.x - m)   + fabsf(c.x - A.x) + fabsf(c.x - A.y);
            s += fabsf(c.y - A.x) + fabsf(c.y - A.y) + fabsf(c.y - A.z);
            s += fabsf(c.z - A.y) + fabsf(c.z - A.z) + fabsf(c.z - A.w);
            s += fabsf(c.w - A.z) + fabsf(c.w - A.w) + fabsf(c.w - q);
        }
    }

    // ---- block reduction + last-block finish ----
    const int lane = tid & 63;
    const int wid  = tid >> 6;
#pragma unroll
    for (int off = 32; off > 0; off >>= 1) s += __shfl_down(s, off, 64);
    if (lane == 0) smem[wid] = s;
    __syncthreads();
    if (tid == 0) {
        const float tsum = smem[0] + smem[1] + smem[2] + smem[3];
        __hip_atomic_store(&partials[bid], tsum, __ATOMIC_RELEASE,
                           __HIP_MEMORY_SCOPE_AGENT);
        const unsigned old = __hip_atomic_fetch_add(counter, 1u, __ATOMIC_ACQ_REL,
                                                    __HIP_MEMORY_SCOPE_AGENT);
        // monotonic counter: correct for any initial value (incl. 0xAA poison)
        lastFlag = ((old & (NBLK - 1)) == (NBLK - 1));
    }
    __syncthreads();

    if (lastFlag) {
        float acc = 0.f;
#pragma unroll
        for (int i = 0; i < NBLK / BLK; ++i)
            acc += __hip_atomic_load(&partials[i * BLK + tid], __ATOMIC_RELAXED,
                                     __HIP_MEMORY_SCOPE_AGENT);
#pragma unroll
        for (int off = 32; off > 0; off >>= 1) acc += __shfl_down(acc, off, 64);
        if (lane == 0) smem[wid] = acc;
        __syncthreads();
        if (tid == 0) {
            const double tot = (double)smem[0] + (double)smem[1] +
                               (double)smem[2] + (double)smem[3];
            out[0] = (float)(tot / (27.0 * (double)NVOX));
        }
    }
}

extern "C" void kernel_launch(void* const* d_in, const int* in_sizes, int n_in,
                              void* d_out, int out_size, void* d_ws, size_t ws_size,
                              hipStream_t stream) {
    const float* x = (const float*)d_in[0];
    const float* y = (const float*)d_in[1];
    float* partials       = (float*)d_ws;
    unsigned int* counter = (unsigned int*)((float*)d_ws + NBLK);
    float* out            = (float*)d_out;

    cdl_kernel<<<NBLK, BLK, 0, stream>>>(x, y, partials, counter, out);
}

// Round 5
// 21.460 us; speedup vs baseline: 1.7791x; 1.7791x over previous
//
#include <hip/hip_runtime.h>

// x,y float32 (B=2, C=1, D=32, H=128, W=128).
// out = mean over [B,C,D,3,H,3,W,3] of |d_c - d_n|, d = x - y, zero-padded
// neighbors. Per voxel: sum |c - n| over all 27 zero-padded neighbors.
constexpr int Dd = 32, Hh = 128, Ww = 128, Bv = 2;
constexpr int NVOX = Bv * Dd * Hh * Ww;     // 1,048,576
constexpr int BLK  = 256;

constexpr int TD = 2, TH = 4;               // tile 2 x 4 x 128 (full W rows)
constexpr int ZT = Dd / TD;                 // 16
constexpr int YT = Hh / TH;                 // 32
constexpr int NBLK = Bv * ZT * YT;          // 1024 blocks = 4/CU
constexpr int LSTR = 136;                   // floats/LDS row; k = w + 4 -> 16B-aligned f4
constexpr int RZ = TD + 2, RY = TH + 2;     // halo: z in [z0-1,z0+2], y in [y0-1,y0+4]
constexpr int NROWS = RZ * RY;              // 24
constexpr int NSLOT = LSTR / 4;             // 34 float4 slots per row
constexpr int NITEM = NROWS * NSLOT;        // 816

__global__ void __launch_bounds__(BLK)
cdl_kernel(const float* __restrict__ xg, const float* __restrict__ yg,
           float* __restrict__ partials, unsigned int* __restrict__ counter,
           float* __restrict__ out)
{
    __shared__ float lds[NROWS * LSTR];     // 13,056 B
    __shared__ float smem[BLK / 64];
    __shared__ int   lastFlag;

    const int tid = threadIdx.x;
    // XCD-aware bijective swizzle (NBLK % 8 == 0)
    const int bid = (blockIdx.x & 7) * (NBLK / 8) + (blockIdx.x >> 3);

    int t = bid;
    const int yt  = t & (YT - 1); t >>= 5;
    const int zt  = t & (ZT - 1); t >>= 4;
    const int vol = t;
    const int z0 = zt * TD, y0 = yt * TH;
    const size_t vbase = (size_t)vol * Dd * Hh * Ww;

    // ---- stage d = x - y halo tile into LDS (zero outside volume / w-pad) ----
#pragma unroll
    for (int p = 0; p < 4; ++p) {
        const int idx = p * BLK + tid;
        if (idx < NITEM) {
            const int row  = idx / NSLOT;
            const int slot = idx - row * NSLOT;
            const int lzr  = row / RY;
            const int lyr  = row - lzr * RY;
            const int gz = z0 + lzr - 1;        // [z0-1, z0+2]
            const int gy = y0 + lyr - 1;        // [y0-1, y0+4]
            const int w  = 4 * slot - 4;        // float4 covers w..w+3
            float4 v = make_float4(0.f, 0.f, 0.f, 0.f);
            if ((unsigned)gz < (unsigned)Dd && (unsigned)gy < (unsigned)Hh &&
                (unsigned)w < (unsigned)Ww) {
                const size_t g = vbase + ((size_t)gz * Hh + gy) * Ww + w;
                const float4 a = *(const float4*)(xg + g);
                const float4 b = *(const float4*)(yg + g);
                v = make_float4(a.x - b.x, a.y - b.y, a.z - b.z, a.w - b.w);
            }
            *(float4*)&lds[row * LSTR + 4 * slot] = v;
        }
    }
    __syncthreads();

    // ---- compute: thread -> one (z,y) row, 4 voxels (w = 4j..4j+3) ----
    const int j  = tid & 31;                    // w-segment
    const int rr = tid >> 5;                    // 0..7
    const int lz = rr >> 2;                     // 0..1
    const int ly = rr & 3;                      // 0..3
    const int k0 = 4 * j + 4;

    const float* crow = &lds[((lz + 1) * RY + (ly + 1)) * LSTR + k0];
    const float4 c = *(const float4*)crow;

    float s = 0.f;
#pragma unroll
    for (int dz = 0; dz < 3; ++dz) {
#pragma unroll
        for (int dy = 0; dy < 3; ++dy) {
            const float* rp = &lds[((lz + dz) * RY + (ly + dy)) * LSTR + k0];
            const float4 A = *(const float4*)rp;
            const float  m = rp[-1];            // w-1 edge
            const float  q = rp[4];             // w+4 edge
            s += fabsf(c.x - m)   + fabsf(c.x - A.x) + fabsf(c.x - A.y);
            s += fabsf(c.y - A.x) + fabsf(c.y - A.y) + fabsf(c.y - A.z);
            s += fabsf(c.z - A.y) + fabsf(c.z - A.z) + fabsf(c.z - A.w);
            s += fabsf(c.w - A.z) + fabsf(c.w - A.w) + fabsf(c.w - q);
        }
    }

    // ---- block reduction ----
    const int lane = tid & 63;
    const int wid  = tid >> 6;
#pragma unroll
    for (int off = 32; off > 0; off >>= 1) s += __shfl_down(s, off, 64);
    if (lane == 0) smem[wid] = s;
    __syncthreads();

    // ---- fence-free publish: relaxed coherent-point atomics only ----
    if (tid == 0) {
        const float tsum = smem[0] + smem[1] + smem[2] + smem[3];
        // atomicExch executes at the coherence point (agent scope), overwrites
        // any previous replay's value -> no init needed, no cache maintenance.
        __hip_atomic_exchange(&partials[bid], tsum, __ATOMIC_RELAXED,
                              __HIP_MEMORY_SCOPE_AGENT);
        // order publish -> counter without any L2 invalidate/writeback:
        asm volatile("s_waitcnt vmcnt(0)" ::: "memory");
        const unsigned old = __hip_atomic_fetch_add(counter, 1u, __ATOMIC_RELAXED,
                                                    __HIP_MEMORY_SCOPE_AGENT);
        // monotonic counter: correct for any initial value (incl. 0xAA poison)
        lastFlag = ((old & (NBLK - 1)) == (NBLK - 1));
    }
    __syncthreads();

    if (lastFlag) {
        float acc = 0.f;
#pragma unroll
        for (int i = 0; i < NBLK / BLK; ++i)
            acc += __hip_atomic_load(&partials[i * BLK + tid], __ATOMIC_RELAXED,
                                     __HIP_MEMORY_SCOPE_AGENT);
#pragma unroll
        for (int off = 32; off > 0; off >>= 1) acc += __shfl_down(acc, off, 64);
        if (lane == 0) smem[wid] = acc;
        __syncthreads();
        if (tid == 0) {
            const double tot = (double)smem[0] + (double)smem[1] +
                               (double)smem[2] + (double)smem[3];
            out[0] = (float)(tot / (27.0 * (double)NVOX));
        }
    }
}

extern "C" void kernel_launch(void* const* d_in, const int* in_sizes, int n_in,
                              void* d_out, int out_size, void* d_ws, size_t ws_size,
                              hipStream_t stream) {
    const float* x = (const float*)d_in[0];
    const float* y = (const float*)d_in[1];
    float* partials       = (float*)d_ws;
    unsigned int* counter = (unsigned int*)((float*)d_ws + NBLK + 64);
    float* out            = (float*)d_out;

    cdl_kernel<<<NBLK, BLK, 0, stream>>>(x, y, partials, counter, out);
}

// Round 6
// 12.193 us; speedup vs baseline: 3.1313x; 1.7601x over previous
//
#include <hip/hip_runtime.h>

// x,y float32 (B=2, C=1, D=32, H=128, W=128).
// out = mean over [B,C,D,3,H,3,W,3] of |d_c - d_n|, d = x - y, zero-padded
// neighbors. Per voxel: sum |c - n| over all 27 zero-padded neighbors.
constexpr int Dd = 32, Hh = 128, Ww = 128, Bv = 2;
constexpr int NVOX = Bv * Dd * Hh * Ww;     // 1,048,576
constexpr int BLK  = 256;

constexpr int TD = 2, TH = 4;               // tile 2 x 4 x 128 (full W rows)
constexpr int ZT = Dd / TD;                 // 16
constexpr int YT = Hh / TH;                 // 32
constexpr int NBLK = Bv * ZT * YT;          // 1024 blocks = 4/CU
constexpr int LSTR = 136;                   // floats/LDS row; k = w + 4 -> 16B-aligned f4
constexpr int RZ = TD + 2, RY = TH + 2;     // halo: z in [z0-1,z0+2], y in [y0-1,y0+4]
constexpr int NROWS = RZ * RY;              // 24
constexpr int NSLOT = LSTR / 4;             // 34 float4 slots per row
constexpr int NITEM = NROWS * NSLOT;        // 816

__global__ void __launch_bounds__(BLK)
cdl_worker(const float* __restrict__ xg, const float* __restrict__ yg,
           float* __restrict__ partials)
{
    __shared__ float lds[NROWS * LSTR];     // 13,056 B
    __shared__ float smem[BLK / 64];

    const int tid = threadIdx.x;
    // XCD-aware bijective swizzle (NBLK % 8 == 0)
    const int bid = (blockIdx.x & 7) * (NBLK / 8) + (blockIdx.x >> 3);

    int t = bid;
    const int yt  = t & (YT - 1); t >>= 5;
    const int zt  = t & (ZT - 1); t >>= 4;
    const int vol = t;
    const int z0 = zt * TD, y0 = yt * TH;
    const size_t vbase = (size_t)vol * Dd * Hh * Ww;

    // ---- stage d = x - y halo tile into LDS (zero outside volume / w-pad) ----
#pragma unroll
    for (int p = 0; p < 4; ++p) {
        const int idx = p * BLK + tid;
        if (idx < NITEM) {
            const int row  = idx / NSLOT;
            const int slot = idx - row * NSLOT;
            const int lzr  = row / RY;
            const int lyr  = row - lzr * RY;
            const int gz = z0 + lzr - 1;        // [z0-1, z0+2]
            const int gy = y0 + lyr - 1;        // [y0-1, y0+4]
            const int w  = 4 * slot - 4;        // float4 covers w..w+3
            float4 v = make_float4(0.f, 0.f, 0.f, 0.f);
            if ((unsigned)gz < (unsigned)Dd && (unsigned)gy < (unsigned)Hh &&
                (unsigned)w < (unsigned)Ww) {
                const size_t g = vbase + ((size_t)gz * Hh + gy) * Ww + w;
                const float4 a = *(const float4*)(xg + g);
                const float4 b = *(const float4*)(yg + g);
                v = make_float4(a.x - b.x, a.y - b.y, a.z - b.z, a.w - b.w);
            }
            *(float4*)&lds[row * LSTR + 4 * slot] = v;
        }
    }
    __syncthreads();

    // ---- compute: thread -> one (z,y) row, 4 voxels (w = 4j..4j+3) ----
    const int j  = tid & 31;                    // w-segment
    const int rr = tid >> 5;                    // 0..7
    const int lz = rr >> 2;                     // 0..1
    const int ly = rr & 3;                      // 0..3
    const int k0 = 4 * j + 4;

    const float* crow = &lds[((lz + 1) * RY + (ly + 1)) * LSTR + k0];
    const float4 c = *(const float4*)crow;

    float s = 0.f;
#pragma unroll
    for (int dz = 0; dz < 3; ++dz) {
#pragma unroll
        for (int dy = 0; dy < 3; ++dy) {
            const float* rp = &lds[((lz + dz) * RY + (ly + dy)) * LSTR + k0];
            const float4 A = *(const float4*)rp;
            const float  m = rp[-1];            // w-1 edge
            const float  q = rp[4];             // w+4 edge
            s += fabsf(c.x - m)   + fabsf(c.x - A.x) + fabsf(c.x - A.y);
            s += fabsf(c.y - A.x) + fabsf(c.y - A.y) + fabsf(c.y - A.z);
            s += fabsf(c.z - A.y) + fabsf(c.z - A.z) + fabsf(c.z - A.w);
            s += fabsf(c.w - A.z) + fabsf(c.w - A.w) + fabsf(c.w - q);
        }
    }

    // ---- block reduction, plain-store publish (flushed at kernel end) ----
    const int lane = tid & 63;
    const int wid  = tid >> 6;
#pragma unroll
    for (int off = 32; off > 0; off >>= 1) s += __shfl_down(s, off, 64);
    if (lane == 0) smem[wid] = s;
    __syncthreads();
    if (tid == 0)
        partials[bid] = smem[0] + smem[1] + smem[2] + smem[3];
}

__global__ void __launch_bounds__(BLK)
cdl_finish(const float* __restrict__ partials, float* __restrict__ out)
{
    float acc = 0.f;
#pragma unroll
    for (int i = 0; i < NBLK / BLK; ++i)
        acc += partials[i * BLK + threadIdx.x];
#pragma unroll
    for (int off = 32; off > 0; off >>= 1) acc += __shfl_down(acc, off, 64);

    __shared__ float smem[BLK / 64];
    const int lane = threadIdx.x & 63;
    const int wid  = threadIdx.x >> 6;
    if (lane == 0) smem[wid] = acc;
    __syncthreads();
    if (threadIdx.x == 0) {
        const double tot = (double)smem[0] + (double)smem[1] +
                           (double)smem[2] + (double)smem[3];
        out[0] = (float)(tot / (27.0 * (double)NVOX));
    }
}

extern "C" void kernel_launch(void* const* d_in, const int* in_sizes, int n_in,
                              void* d_out, int out_size, void* d_ws, size_t ws_size,
                              hipStream_t stream) {
    const float* x = (const float*)d_in[0];
    const float* y = (const float*)d_in[1];
    float* partials = (float*)d_ws;
    float* out      = (float*)d_out;

    cdl_worker<<<NBLK, BLK, 0, stream>>>(x, y, partials);
    cdl_finish<<<1, BLK, 0, stream>>>(partials, out);
}